// Round 5
// baseline (1359.094 us; speedup 1.0000x reference)
//
#include <hip/hip_runtime.h>

#define NN 100000
#define NPAD 100096   // 782 * 128, padded row count for guard-free GEMM
#define NE 600000
#define EMB 128

typedef unsigned short u16;
typedef unsigned int u32;
typedef short short8 __attribute__((ext_vector_type(8)));
typedef float f32x4 __attribute__((ext_vector_type(4)));

__device__ __forceinline__ float4 ld4(const float* p) { return *(const float4*)p; }
__device__ __forceinline__ u16 f2bf(float x) {  // RTNE f32 -> bf16
  u32 u = __float_as_uint(x);
  u += 0x7FFFu + ((u >> 16) & 1u);
  return (u16)(u >> 16);
}
__device__ __forceinline__ float bf2f(u16 h) { return __uint_as_float(((u32)h) << 16); }

// ---------------- node embedding init: hf(f32) + hb(bf16) = emb1[x0] + emb2[x1] ----------------
__global__ __launch_bounds__(256) void node_init_kernel(
    const int* __restrict__ x, const float* __restrict__ emb1,
    const float* __restrict__ emb2, float* __restrict__ hf, u16* __restrict__ hb) {
  int tid = blockIdx.x * blockDim.x + threadIdx.x;
  int n = tid >> 4;
  if (n >= NN) return;
  int kc = tid & 15;
  int x0 = min(max(x[2 * n], 0), 118);
  int x1 = min(max(x[2 * n + 1], 0), 2);  // x[:,1] sampled 0..118 -> clip to NUM_CHIR-1
  const float* p1 = emb1 + (size_t)x0 * EMB + kc * 8;
  const float* p2 = emb2 + (size_t)x1 * EMB + kc * 8;
  float v[8];
#pragma unroll
  for (int j = 0; j < 8; ++j) v[j] = p1[j] + p2[j];
  float* df = hf + (size_t)n * EMB + kc * 8;
  *(float4*)df = make_float4(v[0], v[1], v[2], v[3]);
  *(float4*)(df + 4) = make_float4(v[4], v[5], v[6], v[7]);
  u16 o[8];
#pragma unroll
  for (int j = 0; j < 8; ++j) o[j] = f2bf(v[j]);
  *(ulonglong2*)(hb + (size_t)n * EMB + kc * 8) = *(ulonglong2*)o;
}

// ---------------- CSR build ----------------
__global__ __launch_bounds__(256) void hist_kernel(const int* __restrict__ ei,
                                                   int* __restrict__ deg) {
  int e = blockIdx.x * blockDim.x + threadIdx.x;
  if (e >= NE) return;
  atomicAdd(&deg[ei[NE + e]], 1);
}

__global__ __launch_bounds__(256) void scan1_kernel(const int* __restrict__ deg,
                                                    int* __restrict__ off,
                                                    int* __restrict__ bsum) {
  __shared__ int s[256];
  int t = threadIdx.x;
  int base = blockIdx.x * 1024 + t * 4;
  int v[4];
#pragma unroll
  for (int j = 0; j < 4; ++j) {
    int idx = base + j;
    v[j] = (idx < NN) ? deg[idx] : 0;
  }
  int tsum = v[0] + v[1] + v[2] + v[3];
  s[t] = tsum;
  __syncthreads();
  for (int d = 1; d < 256; d <<= 1) {
    int add = (t >= d) ? s[t - d] : 0;
    __syncthreads();
    s[t] += add;
    __syncthreads();
  }
  int run = s[t] - tsum;
#pragma unroll
  for (int j = 0; j < 4; ++j) {
    int idx = base + j;
    if (idx < NN) off[idx] = run;
    run += v[j];
  }
  if (t == 255) bsum[blockIdx.x] = s[255];
}

__global__ void scan2_kernel(int* __restrict__ bsum, int* __restrict__ off, int nb) {
  if (threadIdx.x == 0) {
    int run = 0;
    for (int b = 0; b < nb; ++b) {
      int v = bsum[b];
      bsum[b] = run;
      run += v;
    }
    off[NN] = run;
  }
}

__global__ __launch_bounds__(256) void scan3_kernel(int* __restrict__ off,
                                                    const int* __restrict__ bsum) {
  int idx = blockIdx.x * blockDim.x + threadIdx.x;
  if (idx < NN) off[idx] += bsum[idx >> 10];
}

__global__ __launch_bounds__(256) void scatter_kernel(
    const int* __restrict__ ei, const int* __restrict__ ea,
    const int* __restrict__ off, int* __restrict__ cnt, int* __restrict__ csr) {
  int e = blockIdx.x * blockDim.x + threadIdx.x;
  if (e >= NE) return;
  int d = ei[NE + e];
  int s = ei[e];
  int a0 = min(max(ea[2 * e], 0), 4);
  int a1 = min(max(ea[2 * e + 1], 0), 2);
  int code = a0 * 3 + a1;  // [0,14]
  int r = atomicAdd(&cnt[d], 1);
  csr[off[d] + r] = s | (code << 20);
}

// combos[l][code][f] = ee1[l][code/3][f] + ee2[l][code%3][f]
__global__ __launch_bounds__(256) void combo_kernel(const float* __restrict__ ee1,
                                                    const float* __restrict__ ee2,
                                                    float* __restrict__ combos) {
  int idx = blockIdx.x * blockDim.x + threadIdx.x;
  if (idx >= 5 * 15 * 128) return;
  int l = idx / (15 * 128);
  int rem = idx % (15 * 128);
  int code = rem / 128;
  int f = rem % 128;
  combos[idx] = ee1[(l * 5 + code / 3) * 128 + f] + ee2[(l * 3 + code % 3) * 128 + f];
}

// ---------------- weight prep: frag-ordered split-bf16 (hi+lo) copies of W1/W2 ----------------
__global__ __launch_bounds__(256) void prep_w_kernel(
    const float* __restrict__ W1g, const float* __restrict__ W2g,
    u16* __restrict__ W1h, u16* __restrict__ W1l,
    u16* __restrict__ W2h, u16* __restrict__ W2l) {
  int idx = blockIdx.x * blockDim.x + threadIdx.x;
  if (idx >= 40960) return;
  u16 oh[8], ol[8];
  if (idx < 20480) {
    int lane = idx & 63;
    int r = idx >> 6;             // l*64 + c*16 + kt*4 + nt
    int nt = r & 3, kt = (r >> 2) & 3, c = (r >> 4) & 3, l = r >> 6;
    int n = c * 64 + nt * 16 + (lane & 15);
    int kb = kt * 32 + (lane >> 4) * 8;
#pragma unroll
    for (int j = 0; j < 8; ++j) {
      float w = W1g[((size_t)l * 128 + kb + j) * 256 + n];
      oh[j] = f2bf(w);
      ol[j] = f2bf(w - bf2f(oh[j]));
    }
    *(ulonglong2*)(W1h + (size_t)idx * 8) = *(ulonglong2*)oh;
    *(ulonglong2*)(W1l + (size_t)idx * 8) = *(ulonglong2*)ol;
  } else {
    int i2 = idx - 20480;
    int lane = i2 & 63;
    int r = i2 >> 6;              // l*64 + c*16 + ktl*8 + nt
    int nt = r & 7, ktl = (r >> 3) & 1, c = (r >> 4) & 3, l = r >> 6;
    int n = nt * 16 + (lane & 15);
    int kb = c * 64 + ktl * 32 + (lane >> 4) * 8;
#pragma unroll
    for (int j = 0; j < 8; ++j) {
      float w = W2g[((size_t)l * 256 + kb + j) * 128 + n];
      oh[j] = f2bf(w);
      ol[j] = f2bf(w - bf2f(oh[j]));
    }
    *(ulonglong2*)(W2h + (size_t)i2 * 8) = *(ulonglong2*)oh;
    *(ulonglong2*)(W2l + (size_t)i2 * 8) = *(ulonglong2*)ol;
  }
}

// ---------------- agg: A = (1+eps)*hf + relu(hf+c0) + sum relu(hb[src]+c), split hi/lo ----------------
__global__ __launch_bounds__(256) void agg_kernel(
    const float* __restrict__ hf, const u16* __restrict__ hb,
    const int* __restrict__ off, const int* __restrict__ csr,
    const float* __restrict__ cb, const float* __restrict__ epsp,
    u16* __restrict__ Ah, u16* __restrict__ Al) {
  int tid = blockIdx.x * blockDim.x + threadIdx.x;
  int g = tid >> 4;
  int kc = tid & 15;
  float av[8] = {0.f, 0.f, 0.f, 0.f, 0.f, 0.f, 0.f, 0.f};
  if (g < NN) {
    const float eps1 = 1.0f + *epsp;
    const float* hp = hf + (size_t)g * EMB + kc * 8;
    float4 va = ld4(hp), vb = ld4(hp + 4);
    float hv[8] = {va.x, va.y, va.z, va.w, vb.x, vb.y, vb.z, vb.w};
    float4 ca = ld4(cb + kc * 8), cbv = ld4(cb + kc * 8 + 4);
    float cs[8] = {ca.x, ca.y, ca.z, ca.w, cbv.x, cbv.y, cbv.z, cbv.w};
#pragma unroll
    for (int j = 0; j < 8; ++j) av[j] = eps1 * hv[j] + fmaxf(hv[j] + cs[j], 0.f);
    int s0 = off[g], s1 = off[g + 1];
    int e = s0;
    for (; e + 1 < s1; e += 2) {  // unroll x2: two independent gather chains in flight
      int p0 = csr[e], p1 = csr[e + 1];
      ulonglong2 r0 = *(const ulonglong2*)(hb + (size_t)(p0 & 0xFFFFF) * EMB + kc * 8);
      ulonglong2 r1 = *(const ulonglong2*)(hb + (size_t)(p1 & 0xFFFFF) * EMB + kc * 8);
      const float* c0p = cb + (size_t)(p0 >> 20) * EMB + kc * 8;
      const float* c1p = cb + (size_t)(p1 >> 20) * EMB + kc * 8;
      float4 c0a = ld4(c0p), c0b = ld4(c0p + 4);
      float4 c1a = ld4(c1p), c1b = ld4(c1p + 4);
      float cc0[8] = {c0a.x, c0a.y, c0a.z, c0a.w, c0b.x, c0b.y, c0b.z, c0b.w};
      float cc1[8] = {c1a.x, c1a.y, c1a.z, c1a.w, c1b.x, c1b.y, c1b.z, c1b.w};
      u16* s0p = (u16*)&r0;
      u16* s1p = (u16*)&r1;
#pragma unroll
      for (int j = 0; j < 8; ++j) {
        av[j] += fmaxf(bf2f(s0p[j]) + cc0[j], 0.f);
        av[j] += fmaxf(bf2f(s1p[j]) + cc1[j], 0.f);
      }
    }
    if (e < s1) {
      int p0 = csr[e];
      ulonglong2 r0 = *(const ulonglong2*)(hb + (size_t)(p0 & 0xFFFFF) * EMB + kc * 8);
      const float* c0p = cb + (size_t)(p0 >> 20) * EMB + kc * 8;
      float4 c0a = ld4(c0p), c0b = ld4(c0p + 4);
      float cc0[8] = {c0a.x, c0a.y, c0a.z, c0a.w, c0b.x, c0b.y, c0b.z, c0b.w};
      u16* s0p = (u16*)&r0;
#pragma unroll
      for (int j = 0; j < 8; ++j) av[j] += fmaxf(bf2f(s0p[j]) + cc0[j], 0.f);
    }
  }
  u16 oh[8], ol[8];
#pragma unroll
  for (int j = 0; j < 8; ++j) {
    oh[j] = f2bf(av[j]);
    ol[j] = f2bf(av[j] - bf2f(oh[j]));
  }
  *(ulonglong2*)(Ah + (size_t)g * EMB + kc * 8) = *(ulonglong2*)oh;  // zeros for pad rows
  *(ulonglong2*)(Al + (size_t)g * EMB + kc * 8) = *(ulonglong2*)ol;
}

// ---------------- mlp: split-bf16 3-product GEMMs; hpre + BN partials ----------------
// 128 rows/block, 4 waves. A hi/lo frags in VGPRs across chunks; Hs hi/lo in LDS (32KB).
__global__ __launch_bounds__(256) void mlp_kernel(
    const u16* __restrict__ Ah, const u16* __restrict__ Al,
    const u16* __restrict__ W1h, const u16* __restrict__ W1l,
    const u16* __restrict__ W2h, const u16* __restrict__ W2l,
    const float* __restrict__ b1g, const float* __restrict__ b2g,
    float* __restrict__ hpre, float* __restrict__ sums) {
  __shared__ __align__(16) u16 Hsh[8 * 2 * 64 * 8];  // hmid hi, A-frag order
  __shared__ __align__(16) u16 Hsl[8 * 2 * 64 * 8];  // hmid lo

  const int t = threadIdx.x;
  const int m0 = blockIdx.x * 128;
  const int w = t >> 6;
  const int lane = t & 63;
  const int quad = lane >> 4, l15 = lane & 15;
  const int wr = w >> 1, wc = w & 1;

  // A fragments (hi+lo) for this wave's rows (32w..32w+31)
  short8 aregh[2][4], aregl[2][4];
#pragma unroll
  for (int mi = 0; mi < 2; ++mi)
#pragma unroll
    for (int kt = 0; kt < 4; ++kt) {
      size_t base = (size_t)(m0 + (2 * w + mi) * 16 + l15) * EMB + kt * 32 + quad * 8;
      aregh[mi][kt] = *(const short8*)(Ah + base);
      aregl[mi][kt] = *(const short8*)(Al + base);
    }

  f32x4 oacc[4][4];
#pragma unroll
  for (int a = 0; a < 4; ++a)
#pragma unroll
    for (int b = 0; b < 4; ++b) oacc[a][b] = (f32x4){0.f, 0.f, 0.f, 0.f};

  for (int c = 0; c < 4; ++c) {
    // stage 1: hmid[:,64c..] = relu(A @ W1[:,c] + b1); 3-product split-bf16
    f32x4 hacc[2][4];
#pragma unroll
    for (int a = 0; a < 2; ++a)
#pragma unroll
      for (int b = 0; b < 4; ++b) hacc[a][b] = (f32x4){0.f, 0.f, 0.f, 0.f};
#pragma unroll
    for (int kt = 0; kt < 4; ++kt) {
#pragma unroll
      for (int nt = 0; nt < 4; ++nt) {
        size_t wb = (((size_t)(c * 4 + kt) * 4 + nt) * 64 + lane) * 8;
        short8 bh = *(const short8*)(W1h + wb);
        short8 bl = *(const short8*)(W1l + wb);
#pragma unroll
        for (int mi = 0; mi < 2; ++mi) {
          hacc[mi][nt] = __builtin_amdgcn_mfma_f32_16x16x32_bf16(aregh[mi][kt], bh, hacc[mi][nt], 0, 0, 0);
          hacc[mi][nt] = __builtin_amdgcn_mfma_f32_16x16x32_bf16(aregl[mi][kt], bh, hacc[mi][nt], 0, 0, 0);
          hacc[mi][nt] = __builtin_amdgcn_mfma_f32_16x16x32_bf16(aregh[mi][kt], bl, hacc[mi][nt], 0, 0, 0);
        }
      }
    }
    __syncthreads();  // previous chunk's GEMM2 reads of Hs are done
    // epilogue: +b1, relu, split hi/lo, scatter to Hs in A-frag order
#pragma unroll
    for (int nt = 0; nt < 4; ++nt) {
      float b1v = b1g[c * 64 + nt * 16 + l15];
      int lcol = nt * 16 + l15;
      int ktl = lcol >> 5;
      int qp = (lcol >> 3) & 3;
      int j = lcol & 7;
#pragma unroll
      for (int mi = 0; mi < 2; ++mi) {
        int mt = 2 * w + mi;
#pragma unroll
        for (int reg = 0; reg < 4; ++reg) {
          float v = fmaxf(hacc[mi][nt][reg] + b1v, 0.f);
          int lp = (quad * 4 + reg) + 16 * qp;
          u16 hi = f2bf(v);
          size_t idx = (((size_t)mt * 2 + ktl) * 64 + lp) * 8 + j;
          Hsh[idx] = hi;
          Hsl[idx] = f2bf(v - bf2f(hi));
        }
      }
    }
    __syncthreads();

    // stage 2: out += hmid_c @ W2[c,:]; 3-product split-bf16; wave (wr,wc) -> 64x64 quadrant
#pragma unroll
    for (int ktl = 0; ktl < 2; ++ktl) {
      short8 a2h[4], a2l[4];
#pragma unroll
      for (int mi = 0; mi < 4; ++mi) {
        size_t idx = (((size_t)(4 * wr + mi) * 2 + ktl) * 64 + lane) * 8;
        a2h[mi] = *(const short8*)&Hsh[idx];
        a2l[mi] = *(const short8*)&Hsl[idx];
      }
#pragma unroll
      for (int nt = 0; nt < 4; ++nt) {
        size_t wb = (((size_t)(c * 2 + ktl) * 8 + wc * 4 + nt) * 64 + lane) * 8;
        short8 bh = *(const short8*)(W2h + wb);
        short8 bl = *(const short8*)(W2l + wb);
#pragma unroll
        for (int mi = 0; mi < 4; ++mi) {
          oacc[mi][nt] = __builtin_amdgcn_mfma_f32_16x16x32_bf16(a2h[mi], bh, oacc[mi][nt], 0, 0, 0);
          oacc[mi][nt] = __builtin_amdgcn_mfma_f32_16x16x32_bf16(a2l[mi], bh, oacc[mi][nt], 0, 0, 0);
          oacc[mi][nt] = __builtin_amdgcn_mfma_f32_16x16x32_bf16(a2h[mi], bl, oacc[mi][nt], 0, 0, 0);
        }
      }
    }
  }

  // final epilogue: +b2, store hpre (f32), BN partial sums
#pragma unroll
  for (int nt = 0; nt < 4; ++nt) {
    int col = wc * 64 + nt * 16 + l15;
    float b2v = b2g[col];
    float s = 0.f, s2 = 0.f;
#pragma unroll
    for (int mi = 0; mi < 4; ++mi) {
      int rowb = m0 + (4 * wr + mi) * 16 + quad * 4;
#pragma unroll
      for (int reg = 0; reg < 4; ++reg) {
        int row = rowb + reg;
        float v = oacc[mi][nt][reg] + b2v;
        if (row < NN) {
          hpre[(size_t)row * EMB + col] = v;
          s += v;
          s2 += v * v;
        }
      }
    }
    s += __shfl_xor(s, 16);
    s += __shfl_xor(s, 32);
    s2 += __shfl_xor(s2, 16);
    s2 += __shfl_xor(s2, 32);
    if (quad == 0) {
      atomicAdd(&sums[col], s);
      atomicAdd(&sums[128 + col], s2);
    }
  }
}

// ---------------- BN apply (stats recomputed inline from sums; L2-hot) ----------------
template <bool LAST>
__global__ __launch_bounds__(256) void bn_apply_kernel(
    const float* __restrict__ hp, const float* __restrict__ sums,
    const float* __restrict__ gamma, const float* __restrict__ beta,
    float* __restrict__ hf, u16* __restrict__ hb, float* __restrict__ out) {
  int tid = blockIdx.x * blockDim.x + threadIdx.x;
  int n = tid >> 4;
  if (n >= NN) return;
  int kc = tid & 15;
  const float* p = hp + (size_t)n * EMB + kc * 8;
  float4 va = ld4(p), vb = ld4(p + 4);
  float v[8] = {va.x, va.y, va.z, va.w, vb.x, vb.y, vb.z, vb.w};
  float4 sa = ld4(sums + kc * 8), sb = ld4(sums + kc * 8 + 4);
  float4 qa = ld4(sums + 128 + kc * 8), qb = ld4(sums + 128 + kc * 8 + 4);
  float4 ga = ld4(gamma + kc * 8), gb = ld4(gamma + kc * 8 + 4);
  float4 ba = ld4(beta + kc * 8), bb = ld4(beta + kc * 8 + 4);
  float sm[8] = {sa.x, sa.y, sa.z, sa.w, sb.x, sb.y, sb.z, sb.w};
  float sq[8] = {qa.x, qa.y, qa.z, qa.w, qb.x, qb.y, qb.z, qb.w};
  float gm[8] = {ga.x, ga.y, ga.z, ga.w, gb.x, gb.y, gb.z, gb.w};
  float bt[8] = {ba.x, ba.y, ba.z, ba.w, bb.x, bb.y, bb.z, bb.w};
#pragma unroll
  for (int j = 0; j < 8; ++j) {
    float mean = sm[j] * (1.0f / NN);
    float var = sq[j] * (1.0f / NN) - mean * mean;  // biased
    float sc = gm[j] * rsqrtf(var + 1e-5f);
    v[j] = (v[j] - mean) * sc + bt[j];
  }
  if (LAST) {
    float* d = out + (size_t)n * EMB + kc * 8;
    *(float4*)d = make_float4(v[0], v[1], v[2], v[3]);
    *(float4*)(d + 4) = make_float4(v[4], v[5], v[6], v[7]);
  } else {
#pragma unroll
    for (int j = 0; j < 8; ++j) v[j] = fmaxf(v[j], 0.f);
    float* df = hf + (size_t)n * EMB + kc * 8;
    *(float4*)df = make_float4(v[0], v[1], v[2], v[3]);
    *(float4*)(df + 4) = make_float4(v[4], v[5], v[6], v[7]);
    u16 o[8];
#pragma unroll
    for (int j = 0; j < 8; ++j) o[j] = f2bf(v[j]);
    *(ulonglong2*)(hb + (size_t)n * EMB + kc * 8) = *(ulonglong2*)o;
  }
}

// ---------------- launch ----------------
extern "C" void kernel_launch(void* const* d_in, const int* in_sizes, int n_in,
                              void* d_out, int out_size, void* d_ws, size_t ws_size,
                              hipStream_t stream) {
  const int* x = (const int*)d_in[0];
  const int* ei = (const int*)d_in[1];
  const int* ea = (const int*)d_in[2];
  const float* x_emb1 = (const float*)d_in[3];
  const float* x_emb2 = (const float*)d_in[4];
  const float* ee1 = (const float*)d_in[5];
  const float* ee2 = (const float*)d_in[6];
  const float* W1 = (const float*)d_in[7];
  const float* b1 = (const float*)d_in[8];
  const float* W2 = (const float*)d_in[9];
  const float* b2 = (const float*)d_in[10];
  const float* eps = (const float*)d_in[11];
  const float* gamma = (const float*)d_in[12];
  const float* beta = (const float*)d_in[13];
  float* out = (float*)d_out;

  // workspace layout (16B-aligned sections)
  float* hpre = (float*)d_ws;                   // NN*128 f32
  float* hf = hpre + (size_t)NN * EMB;          // NN*128 f32
  float* sums = hf + (size_t)NN * EMB;          // 5*256 (per-layer BN partials)
  float* combos = sums + 5 * 256;               // 9600
  u16* Ah = (u16*)(combos + 9600);              // NPAD*128 bf16
  u16* Al = Ah + (size_t)NPAD * EMB;            // NPAD*128 bf16
  u16* hb = Al + (size_t)NPAD * EMB;            // NN*128 bf16
  u16* W1h = hb + (size_t)NN * EMB;             // 5*32768
  u16* W1l = W1h + 5 * 32768;                   // 5*32768
  u16* W2h = W1l + 5 * 32768;                   // 5*32768
  u16* W2l = W2h + 5 * 32768;                   // 5*32768
  int* deg = (int*)(W2l + 5 * 32768);           // NN
  int* off = deg + NN;                          // NN+1
  int* csr = off + NN + 1;                      // NE
  int* bsum = csr + NE;                         // 128

  const int NB_SCAN = (NN + 1023) / 1024;

  // one-time per launch: CSR + combo tables + frag-ordered split-bf16 weights
  hipMemsetAsync(deg, 0, NN * sizeof(int), stream);
  hipMemsetAsync(sums, 0, 5 * 256 * sizeof(float), stream);
  hist_kernel<<<(NE + 255) / 256, 256, 0, stream>>>(ei, deg);
  scan1_kernel<<<NB_SCAN, 256, 0, stream>>>(deg, off, bsum);
  scan2_kernel<<<1, 64, 0, stream>>>(bsum, off, NB_SCAN);
  scan3_kernel<<<(NN + 255) / 256, 256, 0, stream>>>(off, bsum);
  hipMemsetAsync(deg, 0, NN * sizeof(int), stream);
  scatter_kernel<<<(NE + 255) / 256, 256, 0, stream>>>(ei, ea, off, deg, csr);
  combo_kernel<<<(5 * 15 * 128 + 255) / 256, 256, 0, stream>>>(ee1, ee2, combos);
  prep_w_kernel<<<160, 256, 0, stream>>>(W1, W2, W1h, W1l, W2h, W2l);
  node_init_kernel<<<NN * 16 / 256 + 1, 256, 0, stream>>>(x, x_emb1, x_emb2, hf, hb);

  const int NBLK = NPAD / 128;  // 782
  for (int i = 0; i < 5; ++i) {
    agg_kernel<<<NPAD * 16 / 256, 256, 0, stream>>>(
        hf, hb, off, csr, combos + (size_t)i * 15 * EMB, eps + i, Ah, Al);
    mlp_kernel<<<NBLK, 256, 0, stream>>>(
        Ah, Al, W1h + (size_t)i * 32768, W1l + (size_t)i * 32768,
        W2h + (size_t)i * 32768, W2l + (size_t)i * 32768,
        b1 + (size_t)i * 256, b2 + (size_t)i * 128, hpre, sums + i * 256);
    if (i < 4)
      bn_apply_kernel<false><<<NN * 16 / 256 + 1, 256, 0, stream>>>(
          hpre, sums + i * 256, gamma + (size_t)i * EMB, beta + (size_t)i * EMB,
          hf, hb, nullptr);
    else
      bn_apply_kernel<true><<<NN * 16 / 256 + 1, 256, 0, stream>>>(
          hpre, sums + i * 256, gamma + (size_t)i * EMB, beta + (size_t)i * EMB,
          nullptr, nullptr, out);
  }
}